// Round 8
// baseline (57.116 us; speedup 1.0000x reference)
//
#include <hip/hip_runtime.h>
#include <math.h>

#define BATCH 8
#define NN 2048
#define FIN 256
#define FOUT 64
#define ALPHA 0.2f

typedef __attribute__((ext_vector_type(8))) short bf16x8;
typedef __attribute__((ext_vector_type(4))) float f32x4;

static __device__ __forceinline__ unsigned short f2bf(float f) {
  unsigned int u = __float_as_uint(f);
  u += 0x7fffu + ((u >> 16) & 1u);
  return (unsigned short)(u >> 16);
}
static __device__ __forceinline__ float bf2f(unsigned short h) {
  return __uint_as_float(((unsigned int)h) << 16);
}

// ---------------------------------------------------------------------------
// K1: h = x@W via MFMA (hi/lo bf16 split), el/er via shuffle reduce, then
// emit per-64-row pre-swizzled h "staging images" for K2. (unchanged)
// ---------------------------------------------------------------------------
__global__ __launch_bounds__(256) void k1_h(
    const float* __restrict__ x, const float* __restrict__ W,
    const float* __restrict__ a, float* __restrict__ el,
    float* __restrict__ er, unsigned char* __restrict__ hS) {
  __shared__ __align__(16) unsigned short lds[32768];  // 64 KB
  const int t = threadIdx.x;
  const int wv = t >> 6;
  const int l = t & 63;
  const int l15 = l & 15;
  const int kg = l >> 4;

  // phase 0: stage W as bf16 hi/lo planes, XOR-swizzled:
  // u16 idx = plane*16384 + o*256 + ((k>>3)^(o&7))*8 + (k&7)
  {
    const float4* W4 = (const float4*)W;
    #pragma unroll
    for (int i = 0; i < 16; ++i) {
      int f = t + i * 256;            // float4 index, 0..4095
      float4 v = W4[f];
      int k = f >> 4;                 // W row 0..255
      int ob = (f & 15) * 4;
      float vv[4] = {v.x, v.y, v.z, v.w};
      #pragma unroll
      for (int c = 0; c < 4; ++c) {
        int o = ob + c;
        unsigned short hi = f2bf(vv[c]);
        unsigned short lo = f2bf(vv[c] - bf2f(hi));
        int idx = o * 256 + (((k >> 3) ^ (o & 7)) * 8) + (k & 7);
        lds[idx] = hi;
        lds[16384 + idx] = lo;
      }
    }
  }
  __syncthreads();

  const int row = blockIdx.x * 64 + wv * 16 + l15;
  f32x4 acc[4] = {{0.f,0.f,0.f,0.f},{0.f,0.f,0.f,0.f},
                  {0.f,0.f,0.f,0.f},{0.f,0.f,0.f,0.f}};
  const float* xrow = x + (size_t)row * FIN;

  #pragma unroll
  for (int ks = 0; ks < 8; ++ks) {
    int k0 = ks * 32;
    float4 xa = *(const float4*)(xrow + k0 + kg * 8);
    float4 xb = *(const float4*)(xrow + k0 + kg * 8 + 4);
    float xv[8] = {xa.x, xa.y, xa.z, xa.w, xb.x, xb.y, xb.z, xb.w};
    bf16x8 ahi, alo;
    #pragma unroll
    for (int j = 0; j < 8; ++j) {
      unsigned short hi = f2bf(xv[j]);
      unsigned short lo = f2bf(xv[j] - bf2f(hi));
      ahi[j] = (short)hi;
      alo[j] = (short)lo;
    }
    int kgidx = ks * 4 + kg;
    #pragma unroll
    for (int ot = 0; ot < 4; ++ot) {
      int o = ot * 16 + l15;
      int base = o * 256 + ((kgidx ^ (o & 7)) * 8);
      bf16x8 bhi = *(const bf16x8*)&lds[base];
      bf16x8 blo = *(const bf16x8*)&lds[16384 + base];
      acc[ot] = __builtin_amdgcn_mfma_f32_16x16x32_bf16(ahi, bhi, acc[ot], 0, 0, 0);
      acc[ot] = __builtin_amdgcn_mfma_f32_16x16x32_bf16(ahi, blo, acc[ot], 0, 0, 0);
      acc[ot] = __builtin_amdgcn_mfma_f32_16x16x32_bf16(alo, bhi, acc[ot], 0, 0, 0);
    }
  }

  // el/er: reduce across the 16 col-lanes (same kg group)
  float aLv[4], aRv[4];
  #pragma unroll
  for (int ot = 0; ot < 4; ++ot) {
    aLv[ot] = a[ot * 16 + l15];
    aRv[ot] = a[64 + ot * 16 + l15];
  }
  #pragma unroll
  for (int jj = 0; jj < 4; ++jj) {
    float pl = 0.f, pr = 0.f;
    #pragma unroll
    for (int ot = 0; ot < 4; ++ot) {
      pl += acc[ot][jj] * aLv[ot];
      pr += acc[ot][jj] * aRv[ot];
    }
    #pragma unroll
    for (int s = 1; s < 16; s <<= 1) {
      pl += __shfl_xor(pl, s);
      pr += __shfl_xor(pr, s);
    }
    if (l15 == 0) {
      int grow = blockIdx.x * 64 + wv * 16 + kg * 4 + jj;
      el[grow] = pl;
      er[grow] = pr;
    }
  }

  // phase 2: hi/lo split of h, scatter into the image layout (alias lds):
  // u16 idx = ((ks2*2+plane)*64 + o)*32 + (kg2 ^ ((o>>1)&3))*8 + j
  __syncthreads();
  #pragma unroll
  for (int ot = 0; ot < 4; ++ot) {
    int o = ot * 16 + l15;
    int xorv = (o >> 1) & 3;
    #pragma unroll
    for (int jj = 0; jj < 4; ++jj) {
      int m_loc = wv * 16 + kg * 4 + jj;
      int ks2 = m_loc >> 5;
      int kg2 = (m_loc >> 3) & 3;
      int j = m_loc & 7;
      int kgp = kg2 ^ xorv;
      float v = acc[ot][jj];
      unsigned short hi = f2bf(v);
      unsigned short lo = f2bf(v - bf2f(hi));
      int base = ((ks2 * 2 + 0) * 64 + o) * 32 + kgp * 8 + j;
      lds[base] = hi;
      lds[base + 2048] = lo;  // plane stride = 64*32 u16
    }
  }
  __syncthreads();

  // dump 16KB image contiguously to global
  {
    const uint4* src = (const uint4*)(const void*)lds;
    uint4* dst = (uint4*)(hS + (size_t)blockIdx.x * 16384);
    #pragma unroll
    for (int i = 0; i < 4; ++i) dst[t + i * 256] = src[t + i * 256];
  }
}

// ---------------------------------------------------------------------------
// K2: masked-softmax attention as MFMA GEMM — slim high-occupancy version.
// 1024 blocks x 256 thr; block owns 16 n-rows; wave wv owns the disjoint
// m-window [wv*512, wv*512+512) = 16 chunks of 32 m. Register diet:
// acc[4] (one 16-row tile), NO register B-double-buffer (B-frags loaded from
// the L2-resident pre-swizzled image at chunk start, consumed after the
// ~800-cycle j-loop -> L2 latency free), adj 2-chunk-ahead 3-slot rotation,
// er 1-ahead named prefetch. Target <=170 VGPR, 3 waves/SIMD (12 waves/CU).
// No barriers/asm in the main loop. LDS only for the end combine.
// ---------------------------------------------------------------------------
__global__ __launch_bounds__(256, 3) void k2_attn(
    const int* __restrict__ adj, const unsigned char* __restrict__ hS,
    const float* __restrict__ el, const float* __restrict__ er,
    float* __restrict__ out) {
  __shared__ __align__(16) float cb[3 * 64 * 20];  // 15.4 KB combine buffer
  const int t = threadIdx.x;
  const int wv = t >> 6;
  const int l = t & 63;
  const int l15 = l & 15;
  const int kg = l >> 4;

  // XCD-bijective swizzle: 1024 blocks, 128/XCD -> each XCD sees one batch
  int bid = blockIdx.x;
  int swz = (bid & 7) * 128 + (bid >> 3);
  int b = swz >> 7;
  int n0 = (swz & 127) * 16;

  const int row = n0 + l15;
  const float eL = el[b * NN + row];
  const int* arow = adj + (size_t)b * NN * NN + (size_t)row * NN + wv * 512;
  const float* erp = er + b * NN + wv * 512;
  // wave's 16 8KB chunks (32 m each), pre-swizzled image; frag addr is
  // lane-indexed: chunk*8192 + ot*1024 + laneoff (+4096 for lo plane)
  const unsigned char* hW = hS + (size_t)b * 32 * 16384 + (size_t)wv * 16 * 8192;
  const int laneoff = l15 * 64 + ((kg ^ ((l >> 1) & 3)) * 16);

  f32x4 acc[4] = {{0.f,0.f,0.f,0.f},{0.f,0.f,0.f,0.f},
                  {0.f,0.f,0.f,0.f},{0.f,0.f,0.f,0.f}};
  float S = 0.f;

  int4 av[3][2];
  float4 evc0, evc1, evn0, evn1;

  // prologue: adj for chunks 0,1 (2-ahead HBM stream); er chunk 0
  av[0][0] = *(const int4*)(arow + kg * 8);
  av[0][1] = *(const int4*)(arow + kg * 8 + 4);
  av[1][0] = *(const int4*)(arow + 32 + kg * 8);
  av[1][1] = *(const int4*)(arow + 32 + kg * 8 + 4);
  evc0 = *(const float4*)(erp + kg * 8);
  evc1 = *(const float4*)(erp + kg * 8 + 4);

  #pragma unroll
  for (int c = 0; c < 16; ++c) {
    // B-fragments straight from L2 (no double-buffer; consumed after j-loop)
    bf16x8 curH[4], curL[4];
    {
      const unsigned char* p_ = hW + (size_t)c * 8192 + laneoff;
      #pragma unroll
      for (int ot = 0; ot < 4; ++ot) {
        curH[ot] = *(const bf16x8*)(p_ + ot * 1024);
        curL[ot] = *(const bf16x8*)(p_ + ot * 1024 + 4096);
      }
    }
    if (c < 14) {  // adj 2 chunks ahead
      int mb = (c + 2) * 32;
      av[(c + 2) % 3][0] = *(const int4*)(arow + mb + kg * 8);
      av[(c + 2) % 3][1] = *(const int4*)(arow + mb + kg * 8 + 4);
    }
    if (c < 15) {  // er 1 chunk ahead (L2/L3-hot, tiny)
      evn0 = *(const float4*)(erp + (c + 1) * 32 + kg * 8);
      evn1 = *(const float4*)(erp + (c + 1) * 32 + kg * 8 + 4);
    }

    const int sl = c % 3;
    int a0[8] = {av[sl][0].x, av[sl][0].y, av[sl][0].z, av[sl][0].w,
                 av[sl][1].x, av[sl][1].y, av[sl][1].z, av[sl][1].w};
    float ee[8] = {evc0.x, evc0.y, evc0.z, evc0.w,
                   evc1.x, evc1.y, evc1.z, evc1.w};

    bf16x8 afh, afl;
    #pragma unroll
    for (int j = 0; j < 8; ++j) {
      float e0 = eL + ee[j];
      e0 = fmaxf(e0, ALPHA * e0);            // leaky relu
      float w0 = (a0[j] > 0) ? __expf(e0) : 0.f;
      unsigned short h0 = f2bf(w0);
      float w0h = bf2f(h0);
      unsigned short l0 = f2bf(w0 - w0h);
      afh[j] = (short)h0;
      afl[j] = (short)l0;
      S += w0h + bf2f(l0);                   // denom == effective numer weight
    }

    #pragma unroll
    for (int ot = 0; ot < 4; ++ot) {
      acc[ot] = __builtin_amdgcn_mfma_f32_16x16x32_bf16(afh, curH[ot], acc[ot], 0, 0, 0);
      acc[ot] = __builtin_amdgcn_mfma_f32_16x16x32_bf16(afh, curL[ot], acc[ot], 0, 0, 0);
      acc[ot] = __builtin_amdgcn_mfma_f32_16x16x32_bf16(afl, curH[ot], acc[ot], 0, 0, 0);
    }

    if (c < 15) { evc0 = evn0; evc1 = evn1; }  // SSA rename under unroll
  }

  // per-wave S reduce across kg groups (replicates row-l15 denom to all lanes)
  S += __shfl_xor(S, 16);
  S += __shfl_xor(S, 32);

  // cross-wave combine of m-window partials: waves 1..3 publish, wave 0 sums
  __syncthreads();
  if (wv > 0) {
    float* dst = cb + ((wv - 1) * 64 + l) * 20;
    #pragma unroll
    for (int ot = 0; ot < 4; ++ot) *(f32x4*)(dst + ot * 4) = acc[ot];
    dst[16] = S;
  }
  __syncthreads();
  if (wv != 0) return;

  #pragma unroll
  for (int p = 0; p < 3; ++p) {
    const float* src = cb + (p * 64 + l) * 20;
    #pragma unroll
    for (int ot = 0; ot < 4; ++ot) acc[ot] += *(const f32x4*)(src + ot * 4);
    S += src[16];
  }

  float Sj[4];
  #pragma unroll
  for (int jj = 0; jj < 4; ++jj) Sj[jj] = __shfl(S, kg * 4 + jj);
  #pragma unroll
  for (int ot = 0; ot < 4; ++ot) {
    #pragma unroll
    for (int jj = 0; jj < 4; ++jj) {
      float v = acc[ot][jj] / Sj[jj];
      float r = v > 0.f ? v : expm1f(v);
      out[((size_t)b * NN + n0 + kg * 4 + jj) * FOUT + ot * 16 + l15] = r;
    }
  }
}

extern "C" void kernel_launch(void* const* d_in, const int* in_sizes, int n_in,
                              void* d_out, int out_size, void* d_ws, size_t ws_size,
                              hipStream_t stream) {
  const float* x   = (const float*)d_in[0];
  const int*   adj = (const int*)d_in[1];
  const float* W   = (const float*)d_in[2];
  const float* a   = (const float*)d_in[3];
  float* out = (float*)d_out;

  // ws layout: hS images (8*32*16KB = 4MB) | el (64KB) | er (64KB)
  unsigned char* hS = (unsigned char*)d_ws;
  float* el = (float*)(hS + (size_t)BATCH * 32 * 16384);
  float* er = el + BATCH * NN;

  hipLaunchKernelGGL(k1_h, dim3(256), dim3(256), 0, stream, x, W, a, el, er, hS);
  hipLaunchKernelGGL(k2_attn, dim3(1024), dim3(256), 0, stream, adj, hS, el, er, out);
}